// Round 3
// baseline (359.395 us; speedup 1.0000x reference)
//
#include <hip/hip_runtime.h>
#include <math.h>

#define W 480
#define HT 480
#define HW (W*HT)
#define GE (HW/256)     // 900 blocks of 256
#define PP 225
#define NPATCH 1024
#define EQCAP 8192
#define SEG 30          // rows per thread in vertical running-sum kernels (16 segs)

struct State {
  unsigned histA[4][256];   // dark-channel top-k select (descending, k=230)
  unsigned histB[4][256];   // percentile select (ascending, rank 11521)
  float sumA[3];
  unsigned eqCount;
  float A[3];
  unsigned eqIdx[EQCAP];
  float tp1[NPATCH];
  float tp2[NPATCH];
};

// ---------- cooperative radix-select resolve ----------
__device__ __forceinline__ void resolve_level(const unsigned* __restrict__ h,
                                              unsigned k_in, int desc,
                                              unsigned* lds,
                                              unsigned& chosen, unsigned& k_out) {
  int t = threadIdx.x;
  unsigned c = h[desc ? (255 - t) : t];
  lds[t] = c;
  __syncthreads();
  for (int s = 1; s < 256; s <<= 1) {           // Hillis-Steele inclusive scan
    unsigned add = (t >= s) ? lds[t - s] : 0u;
    __syncthreads();
    lds[t] += add;
    __syncthreads();
  }
  unsigned incl = lds[t];
  unsigned excl = incl - c;
  if (incl >= k_in && excl < k_in) { lds[256] = (unsigned)t; lds[257] = k_in - excl; }
  __syncthreads();
  unsigned tt = lds[256];
  k_out = lds[257];
  chosen = desc ? (255u - tt) : tt;
  __syncthreads();
}

__device__ __forceinline__ void resolve_prefix(const unsigned (*hist)[256], unsigned k0,
                                               int desc, int levels, unsigned* lds,
                                               unsigned& bits, unsigned& kf) {
  unsigned prefix = 0u, k = k0;
  for (int j = 0; j < levels; ++j) {
    unsigned ch, kn;
    resolve_level(hist[j], k, desc, lds, ch, kn);
    prefix |= ch << (24 - 8 * j);
    k = kn;
  }
  bits = prefix; kf = k;
}

// ---------- stage 0: init state + channel-min ----------
__global__ __launch_bounds__(256) void k0_init_dmin(const float* __restrict__ img,
                                                    float* __restrict__ out, State* st) {
  int t = threadIdx.x;
  int p = blockIdx.x * 256 + t;
  out[p] = fminf(fminf(img[p], img[HW + p]), img[2 * HW + p]);
  if (blockIdx.x == 0) {
    for (int i = 0; i < 4; ++i) { st->histA[i][t] = 0u; st->histB[i][t] = 0u; }
    if (t == 0) { st->sumA[0] = 0.f; st->sumA[1] = 0.f; st->sumA[2] = 0.f; st->eqCount = 0u; }
  }
}

// ---------- horizontal 55-min (pad 1.0) ----------
__global__ __launch_bounds__(256) void k_minH(const float* __restrict__ in, float* __restrict__ out) {
  int p = blockIdx.x * 256 + threadIdx.x;
  int y = p / W, x = p - y * W;
  float m = INFINITY;
  for (int d = -27; d <= 27; ++d) {
    int xx = x + d;
    float v = ((unsigned)xx < (unsigned)W) ? in[y * W + xx] : 1.0f;
    m = fminf(m, v);
  }
  out[p] = m;
}

// ---------- vertical 8-row chunk mins (exact; 60 chunks x 480 cols) ----------
__global__ __launch_bounds__(256) void k_vchunk(const float* __restrict__ rowmin,
                                                float* __restrict__ cmin) {
  int p = blockIdx.x * 256 + threadIdx.x;
  if (p >= 60 * W) return;
  int c = p / W, x = p - c * W;
  float m = INFINITY;
  for (int r = 0; r < 8; ++r) m = fminf(m, rowmin[(c * 8 + r) * W + x]);
  cmin[p] = m;
}

// ---------- vertical 55-min via chunks + edges (exact), fused histA level-0 ----------
__global__ __launch_bounds__(256) void k_minV2(const float* __restrict__ rowmin,
                                               const float* __restrict__ cmin,
                                               float* __restrict__ dc, State* st) {
  __shared__ unsigned lh[256];
  int t = threadIdx.x;
  lh[t] = 0u;
  __syncthreads();
  int p = blockIdx.x * 256 + t;
  int y = p / W, x = p - y * W;
  int lo = y - 27, hi = y + 27;
  float m = (lo < 0 || hi >= HT) ? 1.0f : INFINITY;   // pad value 1.0 (dc <= 1)
  int lo2 = max(lo, 0), hi2 = min(hi, HT - 1);
  int cs = (lo2 + 7) >> 3, ce = ((hi2 + 1) >> 3) - 1;
  for (int c = cs; c <= ce; ++c) m = fminf(m, cmin[c * W + x]);
  for (int yy = lo2; yy < (cs << 3); ++yy) m = fminf(m, rowmin[yy * W + x]);
  for (int yy = (ce + 1) << 3; yy <= hi2; ++yy) m = fminf(m, rowmin[yy * W + x]);
  dc[p] = m;
  atomicAdd(&lh[__float_as_uint(m) >> 24], 1u);
  __syncthreads();
  unsigned c = lh[t];
  if (c) atomicAdd(&st->histA[0][t], c);
}

// ---------- radix histogram pass, levels 1..3 ----------
__global__ __launch_bounds__(256) void k_hist(const float* __restrict__ data,
                                              unsigned (*hist)[256],
                                              int level, unsigned k0, int desc, int z2t) {
  __shared__ unsigned lds[258];
  int t = threadIdx.x;
  unsigned prefix = 0u, k = k0;
  for (int j = 0; j < level; ++j) {
    unsigned ch, kn;
    resolve_level(hist[j], k, desc, lds, ch, kn);
    prefix |= ch << (24 - 8 * j);
    k = kn;
  }
  lds[t] = 0u;
  __syncthreads();
  int p = blockIdx.x * 256 + t;
  float v = data[p];
  if (z2t) v = (v > 0.0f) ? v : 10.0f;
  unsigned bits = __float_as_uint(v);
  unsigned mask = 0xFFFFFFFFu << (32 - 8 * level);
  if ((bits & mask) == prefix)
    atomicAdd(&lds[(bits >> (24 - 8 * level)) & 0xFFu], 1u);
  __syncthreads();
  unsigned c = lds[t];
  if (c) atomicAdd(&hist[level][t], c);
}

// ---------- airlight gather ----------
__global__ __launch_bounds__(256) void k_gatherA(const float* __restrict__ dc,
                                                 const float* __restrict__ img, State* st) {
  __shared__ unsigned lds[258];
  unsigned vb, kf;
  resolve_prefix(st->histA, 230u, 1, 4, lds, vb, kf);
  int p = blockIdx.x * 256 + threadIdx.x;
  unsigned bits = __float_as_uint(dc[p]);
  if (bits > vb) {
    atomicAdd(&st->sumA[0], img[p]);
    atomicAdd(&st->sumA[1], img[HW + p]);
    atomicAdd(&st->sumA[2], img[2 * HW + p]);
  } else if (bits == vb) {
    unsigned pos = atomicAdd(&st->eqCount, 1u);
    if (pos < (unsigned)EQCAP) st->eqIdx[pos] = (unsigned)p;
  }
}

// lax.top_k tie-break = lower index first: keq smallest indices among equals
__global__ __launch_bounds__(256) void k_finalizeA(const float* __restrict__ img, State* st) {
  __shared__ unsigned lds[258];
  __shared__ unsigned sIdx[EQCAP];
  __shared__ float ssum[3];
  unsigned vb, keq;
  resolve_prefix(st->histA, 230u, 1, 4, lds, vb, keq);
  int t = threadIdx.x;
  unsigned ne = st->eqCount; if (ne > (unsigned)EQCAP) ne = EQCAP;
  for (int i = t; i < (int)ne; i += 256) sIdx[i] = st->eqIdx[i];
  if (t < 3) ssum[t] = 0.f;
  __syncthreads();
  unsigned lo = 0u, hi = HW;
  while (hi - lo > 1u) {
    unsigned mid = (lo + hi) >> 1;
    unsigned c = 0u;
    for (int i = t; i < (int)ne; i += 256) c += (sIdx[i] < mid) ? 1u : 0u;
    lds[t] = c; __syncthreads();
    for (int s = 128; s > 0; s >>= 1) { if (t < s) lds[t] += lds[t + s]; __syncthreads(); }
    unsigned total = lds[0];
    __syncthreads();
    if (total >= keq) hi = mid; else lo = mid;
  }
  float a0 = 0.f, a1 = 0.f, a2 = 0.f;
  for (int i = t; i < (int)ne; i += 256) {
    unsigned q = sIdx[i];
    if (q < hi) { a0 += img[q]; a1 += img[HW + q]; a2 += img[2 * HW + q]; }
  }
  atomicAdd(&ssum[0], a0); atomicAdd(&ssum[1], a1); atomicAdd(&ssum[2], a2);
  __syncthreads();
  if (t == 0) {
    st->A[0] = (st->sumA[0] + ssum[0]) / 230.0f;
    st->A[1] = (st->sumA[1] + ssum[1]) / 230.0f;
    st->A[2] = (st->sumA[2] + ssum[2]) / 230.0f;
  }
}

// ---------- S, V1, I, bccr pre-pool map ----------
__global__ __launch_bounds__(256) void k_elem1(const float* __restrict__ img,
                                               const State* __restrict__ st,
                                               float* __restrict__ So, float* __restrict__ Vo,
                                               float* __restrict__ Io, float* __restrict__ To) {
  int p = blockIdx.x * 256 + threadIdx.x;
  float A0 = st->A[0], A1 = st->A[1], A2 = st->A[2];
  float r = img[p], g = img[HW + p], bl = img[2 * HW + p];
  float nr = r / A0, ng = g / A1, nb = bl / A2;
  float mx = fmaxf(fmaxf(nr, ng), nb);
  float mn = fminf(fminf(nr, ng), nb);
  float d = mx + 1e-8f;
  So[p] = 1.0f - mn / d;
  Vo[p] = 1.0f / d;
  Io[p] = ((r + g) + bl) / 3.0f;
  const float c20 = (float)(20.0 / 255.0);
  const float c300 = (float)(300.0 / 255.0);
  float t0 = fmaxf((A0 - r) / (A0 - c20), (A0 - r) / (A0 - c300));
  float t1 = fmaxf((A1 - g) / (A1 - c20), (A1 - g) / (A1 - c300));
  float t2 = fmaxf((A2 - bl) / (A2 - c20), (A2 - bl) / (A2 - c300));
  To[p] = fmaxf(fmaxf(t0, t1), t2);
}

// ---------- wave reductions ----------
__device__ __forceinline__ float wred_sum(float v) { for (int m = 32; m; m >>= 1) v += __shfl_xor(v, m, 64); return v; }
__device__ __forceinline__ float wred_max(float v) { for (int m = 32; m; m >>= 1) v = fmaxf(v, __shfl_xor(v, m, 64)); return v; }
__device__ __forceinline__ float wred_min(float v) { for (int m = 32; m; m >>= 1) v = fminf(v, __shfl_xor(v, m, 64)); return v; }

// ---------- mega1: both patch grids (division-free slope test) + bccr H-maxpool ----------
__global__ __launch_bounds__(256) void k_mega1(const float* __restrict__ Sv,
                                               const float* __restrict__ Vv,
                                               const float* __restrict__ To,
                                               float* __restrict__ mh, State* st) {
  __shared__ float2 XY[PP];
  __shared__ float part[4][8];
  int b = blockIdx.x;
  int t = threadIdx.x;
  if (b >= 2048) {   // bccr 15-tap horizontal max (pad 0)
    int p = (b - 2048) * 256 + t;
    int y = p / W, x = p - y * W;
    float m = -INFINITY;
    for (int d = -7; d <= 7; ++d) {
      int xx = x + d;
      float v = ((unsigned)xx < (unsigned)W) ? To[y * W + xx] : 0.0f;
      m = fmaxf(m, v);
    }
    mh[p] = m;
    return;
  }
  int mode = b >> 10;              // 0: t1 grid, 1: shifted t2 grid
  int pid = b & 1023;
  int ph = pid >> 5, pw = pid & 31;
  if (t < PP) {
    int r = t / 15, c = t - (t / 15) * 15;
    int y, x;
    if (mode == 0) { y = ph * 15 + r; x = pw * 15 + c; }
    else {
      y = ph * 15 + r + 4; y = (y < 7) ? 7 : ((y > 479) ? 479 : y);
      x = pw * 15 + c + 4; x = (x < 7) ? 7 : ((x > 479) ? 479 : x);
    }
    float2 v; v.x = Vv[y * W + x]; v.y = Sv[y * W + x];
    XY[t] = v;
  }
  __syncthreads();
  float xi = 0.f, yi = 0.f;
  int cnt = 0;
  if (t < PP) {
    xi = XY[t].x; yi = XY[t].y;
    // slope = dY/(dX+1e-8) in (-1,0)  <=>  sign-resolved compares (no division):
    //   D>0: -D < dY < 0 ;  D<0: 0 < dY < -D ;  D==0: false
    for (int j = 0; j < PP; ++j) {
      float2 o = XY[j];
      float dY = yi - o.y;
      float D = (xi - o.x) + 1e-8f;
      float nD = -D;
      bool c = (D > 0.0f) ? ((dY < 0.0f) && (dY > nD))
                          : ((D < 0.0f) && (dY > 0.0f) && (dY < nD));
      cnt += c ? 1 : 0;
    }
  }
  float pmf = (t < PP && cnt >= 113) ? 1.0f : 0.0f;   // scount >= 112.5
  float xm = xi * pmf, ym = yi * pmf;
  float v0 = wred_sum(pmf);
  float v1 = wred_sum(xm);
  float v2 = wred_sum(ym);
  float v3 = wred_sum(xm * ym);
  float v4 = wred_sum(xm * xm);
  float v5 = wred_max((t < PP) ? xm : -INFINITY);
  float v6 = wred_min((t < PP) ? (xi + 1e8f * (1.0f - pmf)) : INFINITY);
  int wid = t >> 6, lane = t & 63;
  if (lane == 0) {
    part[wid][0] = v0; part[wid][1] = v1; part[wid][2] = v2; part[wid][3] = v3;
    part[wid][4] = v4; part[wid][5] = v5; part[wid][6] = v6;
  }
  __syncthreads();
  if (t == 0) {
    float pcount = 0.f, sx = 0.f, sy = 0.f, sxy = 0.f, sxx = 0.f;
    float mxX = -INFINITY, mnX = INFINITY;
    for (int w2 = 0; w2 < 4; ++w2) {
      pcount += part[w2][0]; sx += part[w2][1]; sy += part[w2][2];
      sxy += part[w2][3]; sxx += part[w2][4];
      mxX = fmaxf(mxX, part[w2][5]); mnX = fminf(mnX, part[w2][6]);
    }
    float den = pcount + 1e-5f;
    float mxv = sx / den, myv = sy / den;
    float kk = (sxy - pcount * mxv * myv) / (sxx - pcount * (mxv * mxv) + 1e-5f);
    float bb = myv - kk * mxv;
    float tt = 1.0f + kk / (bb + 1e-8f);
    float len = sqrtf(1.0f + kk * kk) * (mxX - mnX);
    bool m = (pcount > 10.0f) && (len > 0.1f) && (kk > -1.0f) && (kk < 0.0f)
             && (tt > 0.01f) && (tt < 0.99f);
    float res = tt * (m ? 1.0f : 0.0f);   // keep JAX NaN*0 semantics
    if (mode == 0) st->tp1[pid] = res; else st->tp2[pid] = res;
  }
}

// ---------- mega2: t_slp fusion (+histB level-0) | bccr V-maxpool+clip ----------
__global__ __launch_bounds__(256) void k_mega2(State* st,
                                               const float* __restrict__ mh,
                                               float* __restrict__ ts_out,
                                               float* __restrict__ tb_out) {
  __shared__ unsigned lh[256];
  int b = blockIdx.x;
  int t = threadIdx.x;
  if (b < GE) {
    lh[t] = 0u;
    __syncthreads();
    int p = b * 256 + t;
    int y = p / W, x = p - y * W;
    float a = st->tp1[(y / 15) * 32 + (x / 15)];
    float bb = 0.0f;
    if (y >= 7 && x >= 7) bb = st->tp2[((y - 4) / 15) * 32 + ((x - 4) / 15)];
    float r;
    if (a != 0.0f && bb != 0.0f) r = (a + bb) / 2.0f;   // NaN != 0 true, as in JAX
    else r = (a != 0.0f) ? a : bb;
    ts_out[p] = r;
    float u = (r > 0.0f) ? r : 10.0f;                   // where(t>0,t,10); NaN->10
    atomicAdd(&lh[__float_as_uint(u) >> 24], 1u);
    __syncthreads();
    unsigned c = lh[t];
    if (c) atomicAdd(&st->histB[0][t], c);
  } else {
    int p = (b - GE) * 256 + t;
    int y = p / W, x = p - y * W;
    float m = -INFINITY;
    for (int d = -7; d <= 7; ++d) {
      int yy = y + d;
      float v = ((unsigned)yy < (unsigned)HT) ? mh[yy * W + x] : 0.0f;
      m = fmaxf(m, v);
    }
    tb_out[p] = fminf(fmaxf(m, 0.05f), 1.0f);
  }
}

// ---------- t_fusion ----------
__global__ __launch_bounds__(256) void k_fusion(const float* __restrict__ ts,
                                                const float* __restrict__ tb,
                                                const State* __restrict__ st,
                                                float* __restrict__ out) {
  __shared__ unsigned lds[258];
  unsigned vb, kf;
  resolve_prefix(st->histB, 11521u, 0, 4, lds, vb, kf);
  float tmin = __uint_as_float(vb);
  int p = blockIdx.x * 256 + threadIdx.x;
  float x = ts[p];
  float v = (x > 0.0f) ? x : tb[p];
  v = (v < tmin) ? tmin : v;
  v = (v > 1.0f) ? 1.0f : v;
  out[p] = v;
}

// ---------- guided filter r=30 eps=1e-3 ----------
__global__ __launch_bounds__(256) void k_gf1h(const float* __restrict__ I, const float* __restrict__ P,
                                              float* __restrict__ oI, float* __restrict__ oP,
                                              float* __restrict__ oIp, float* __restrict__ oII) {
  int p = blockIdx.x * 256 + threadIdx.x;
  int y = p / W, x = p - y * W;
  float sI = 0.f, sP = 0.f, sIp = 0.f, sII = 0.f;
  for (int d = -30; d <= 30; ++d) {
    int xx = x + d;
    if ((unsigned)xx < (unsigned)W) {
      float iv = I[y * W + xx], pv = P[y * W + xx];
      sI += iv; sP += pv; sIp += iv * pv; sII += iv * iv;
    }
  }
  oI[p] = sI; oP[p] = sP; oIp[p] = sIp; oII[p] = sII;
}

// vertical pass 1 as per-column running window (30 blocks)
__global__ __launch_bounds__(256) void k_gf1v_run(const float* __restrict__ hI, const float* __restrict__ hP,
                                                  const float* __restrict__ hIp, const float* __restrict__ hII,
                                                  float* __restrict__ ao, float* __restrict__ bo) {
  int g = blockIdx.x * 256 + threadIdx.x;   // 7680 = 480 cols * 16 segs
  int x = g % W;
  int y0 = (g / W) * SEG;
  float sI = 0.f, sP = 0.f, sIp = 0.f, sII = 0.f;
  int lo = max(y0 - 30, 0), hi = min(y0 + 30, HT - 1);
  for (int yy = lo; yy <= hi; ++yy) {
    int q = yy * W + x;
    sI += hI[q]; sP += hP[q]; sIp += hIp[q]; sII += hII[q];
  }
  int nxl = min(x + 30, W - 1) - max(x - 30, 0) + 1;
  for (int r = 0; r < SEG; ++r) {
    int y = y0 + r;
    if (r) {
      int ya = y + 30;
      if (ya < HT) { int q = ya * W + x; sI += hI[q]; sP += hP[q]; sIp += hIp[q]; sII += hII[q]; }
      int yr = y - 31;
      if (yr >= 0) { int q = yr * W + x; sI -= hI[q]; sP -= hP[q]; sIp -= hIp[q]; sII -= hII[q]; }
    }
    int ny = min(y + 30, HT - 1) - max(y - 30, 0) + 1;
    float Nn = (float)(ny * nxl);
    float mI = sI / Nn, mP = sP / Nn, mIp = sIp / Nn, mII = sII / Nn;
    float cov = mIp - mI * mP;
    float var = mII - mI * mI;
    float av = cov / (var + 1e-3f);
    int q = y * W + x;
    ao[q] = av;
    bo[q] = mP - av * mI;
  }
}

__global__ __launch_bounds__(256) void k_gf2h(const float* __restrict__ a, const float* __restrict__ b,
                                              float* __restrict__ oa, float* __restrict__ ob) {
  int p = blockIdx.x * 256 + threadIdx.x;
  int y = p / W, x = p - y * W;
  float sa = 0.f, sb = 0.f;
  for (int d = -30; d <= 30; ++d) {
    int xx = x + d;
    if ((unsigned)xx < (unsigned)W) { sa += a[y * W + xx]; sb += b[y * W + xx]; }
  }
  oa[p] = sa; ob[p] = sb;
}

// vertical pass 2 + restore epilogue as running window (30 blocks)
__global__ __launch_bounds__(256) void k_gf2v_run(const float* __restrict__ ha, const float* __restrict__ hb,
                                                  const float* __restrict__ I, const float* __restrict__ img,
                                                  const State* __restrict__ st, float* __restrict__ out) {
  int g = blockIdx.x * 256 + threadIdx.x;
  int x = g % W;
  int y0 = (g / W) * SEG;
  float A0 = st->A[0], A1 = st->A[1], A2 = st->A[2];
  float sa = 0.f, sb = 0.f;
  int lo = max(y0 - 30, 0), hi = min(y0 + 30, HT - 1);
  for (int yy = lo; yy <= hi; ++yy) { int q = yy * W + x; sa += ha[q]; sb += hb[q]; }
  int nxl = min(x + 30, W - 1) - max(x - 30, 0) + 1;
  for (int r = 0; r < SEG; ++r) {
    int y = y0 + r;
    if (r) {
      int ya = y + 30;
      if (ya < HT) { int q = ya * W + x; sa += ha[q]; sb += hb[q]; }
      int yr = y - 31;
      if (yr >= 0) { int q = yr * W + x; sa -= ha[q]; sb -= hb[q]; }
    }
    int ny = min(y + 30, HT - 1) - max(y - 30, 0) + 1;
    float Nn = (float)(ny * nxl);
    int p = y * W + x;
    float tref = (sa / Nn) * I[p] + (sb / Nn);
    out[p]          = (img[p]          - A0) / tref + A0;
    out[HW + p]     = (img[HW + p]     - A1) / tref + A1;
    out[2 * HW + p] = (img[2 * HW + p] - A2) / tref + A2;
  }
}

// ---------- launch: 20 dispatches ----------
extern "C" void kernel_launch(void* const* d_in, const int* in_sizes, int n_in,
                              void* d_out, int out_size, void* d_ws, size_t ws_size,
                              hipStream_t stream) {
  (void)in_sizes; (void)n_in; (void)out_size; (void)ws_size;
  const float* img = (const float*)d_in[0];
  float* out = (float*)d_out;
  State* st = (State*)d_ws;
  float* sb = (float*)((char*)d_ws + 65536);
  float* s0 = sb + 0 * HW;  // dmin -> dc -> t_slp
  float* s1 = sb + 1 * HW;  // minH temp -> bccr map -> t_bl
  float* s2 = sb + 2 * HW;  // S -> a
  float* s3 = sb + 3 * HW;  // V1 -> b
  float* s4 = sb + 4 * HW;  // I (channel mean)
  float* s5 = sb + 5 * HW;  // cmin (28800) -> maxH temp -> t_fusion
  float* s6 = sb + 6 * HW;  // box temps
  float* s7 = sb + 7 * HW;
  float* s8 = sb + 8 * HW;
  float* s9 = sb + 9 * HW;

  dim3 blk(256);
  dim3 ge(GE);

  k0_init_dmin<<<ge, blk, 0, stream>>>(img, s0, st);
  k_minH<<<ge, blk, 0, stream>>>(s0, s1);
  k_vchunk<<<dim3(113), blk, 0, stream>>>(s1, s5);
  k_minV2<<<ge, blk, 0, stream>>>(s1, s5, s0, st);          // dc + histA[0]

  for (int l = 1; l < 4; ++l)
    k_hist<<<ge, blk, 0, stream>>>(s0, st->histA, l, 230u, 1, 0);
  k_gatherA<<<ge, blk, 0, stream>>>(s0, img, st);
  k_finalizeA<<<dim3(1), blk, 0, stream>>>(img, st);

  k_elem1<<<ge, blk, 0, stream>>>(img, st, s2, s3, s4, s1);

  k_mega1<<<dim3(2048 + GE), blk, 0, stream>>>(s2, s3, s1, s5, st);
  k_mega2<<<dim3(2 * GE), blk, 0, stream>>>(st, s5, s0, s1); // t_slp + histB[0] | t_bl

  for (int l = 1; l < 4; ++l)
    k_hist<<<ge, blk, 0, stream>>>(s0, st->histB, l, 11521u, 0, 1);

  k_fusion<<<ge, blk, 0, stream>>>(s0, s1, st, s5);
  k_gf1h<<<ge, blk, 0, stream>>>(s4, s5, s6, s7, s8, s9);
  k_gf1v_run<<<dim3(30), blk, 0, stream>>>(s6, s7, s8, s9, s2, s3);
  k_gf2h<<<ge, blk, 0, stream>>>(s2, s3, s6, s7);
  k_gf2v_run<<<dim3(30), blk, 0, stream>>>(s6, s7, s4, img, st, out);
}

// Round 4
// 266.200 us; speedup vs baseline: 1.3501x; 1.3501x over previous
//
#include <hip/hip_runtime.h>
#include <math.h>

#define W 480
#define HT 480
#define HW (W*HT)
#define GE (HW/256)     // 900 blocks of 256
#define PP 225
#define NPATCH 1024
#define EQCAP 8192

struct State {
  unsigned histA[4][256];   // dark-channel top-k select (descending, k=230)
  float sumA[3];
  unsigned eqCount;
  float A[3];
  unsigned tminbits;        // percentile result (float bits)
  unsigned eqIdx[EQCAP];
  float tp1[NPATCH];
  float tp2[NPATCH];
};

// ---------- cooperative radix-select resolve ----------
__device__ __forceinline__ void resolve_level(const unsigned* __restrict__ h,
                                              unsigned k_in, int desc,
                                              unsigned* lds,
                                              unsigned& chosen, unsigned& k_out) {
  int t = threadIdx.x;
  unsigned c = h[desc ? (255 - t) : t];
  lds[t] = c;
  __syncthreads();
  for (int s = 1; s < 256; s <<= 1) {           // Hillis-Steele inclusive scan
    unsigned add = (t >= s) ? lds[t - s] : 0u;
    __syncthreads();
    lds[t] += add;
    __syncthreads();
  }
  unsigned incl = lds[t];
  unsigned excl = incl - c;
  if (incl >= k_in && excl < k_in) { lds[256] = (unsigned)t; lds[257] = k_in - excl; }
  __syncthreads();
  unsigned tt = lds[256];
  k_out = lds[257];
  chosen = desc ? (255u - tt) : tt;
  __syncthreads();
}

__device__ __forceinline__ void resolve_prefix(const unsigned (*hist)[256], unsigned k0,
                                               int desc, int levels, unsigned* lds,
                                               unsigned& bits, unsigned& kf) {
  unsigned prefix = 0u, k = k0;
  for (int j = 0; j < levels; ++j) {
    unsigned ch, kn;
    resolve_level(hist[j], k, desc, lds, ch, kn);
    prefix |= ch << (24 - 8 * j);
    k = kn;
  }
  bits = prefix; kf = k;
}

// ---------- stage 0: init state + channel-min ----------
__global__ __launch_bounds__(256) void k0_init_dmin(const float* __restrict__ img,
                                                    float* __restrict__ out, State* st) {
  int t = threadIdx.x;
  int p = blockIdx.x * 256 + t;
  out[p] = fminf(fminf(img[p], img[HW + p]), img[2 * HW + p]);
  if (blockIdx.x == 0) {
    for (int i = 0; i < 4; ++i) st->histA[i][t] = 0u;
    if (t == 0) { st->sumA[0] = 0.f; st->sumA[1] = 0.f; st->sumA[2] = 0.f; st->eqCount = 0u; }
  }
}

// ---------- horizontal 55-min (pad 1.0) ----------
__global__ __launch_bounds__(256) void k_minH(const float* __restrict__ in, float* __restrict__ out) {
  int p = blockIdx.x * 256 + threadIdx.x;
  int y = p / W, x = p - y * W;
  float m = INFINITY;
  for (int d = -27; d <= 27; ++d) {
    int xx = x + d;
    float v = ((unsigned)xx < (unsigned)W) ? in[y * W + xx] : 1.0f;
    m = fminf(m, v);
  }
  out[p] = m;
}

// ---------- vertical 8-row chunk mins (exact; 60 chunks x 480 cols) ----------
__global__ __launch_bounds__(256) void k_vchunk(const float* __restrict__ rowmin,
                                                float* __restrict__ cmin) {
  int p = blockIdx.x * 256 + threadIdx.x;
  if (p >= 60 * W) return;
  int c = p / W, x = p - c * W;
  float m = INFINITY;
  for (int r = 0; r < 8; ++r) m = fminf(m, rowmin[(c * 8 + r) * W + x]);
  cmin[p] = m;
}

// ---------- vertical 55-min via chunks + edges (exact), fused histA level-0 ----------
__global__ __launch_bounds__(256) void k_minV2(const float* __restrict__ rowmin,
                                               const float* __restrict__ cmin,
                                               float* __restrict__ dc, State* st) {
  __shared__ unsigned lh[256];
  int t = threadIdx.x;
  lh[t] = 0u;
  __syncthreads();
  int p = blockIdx.x * 256 + t;
  int y = p / W, x = p - y * W;
  int lo = y - 27, hi = y + 27;
  float m = (lo < 0 || hi >= HT) ? 1.0f : INFINITY;   // pad value 1.0 (dc <= 1)
  int lo2 = max(lo, 0), hi2 = min(hi, HT - 1);
  int cs = (lo2 + 7) >> 3, ce = ((hi2 + 1) >> 3) - 1;
  for (int c = cs; c <= ce; ++c) m = fminf(m, cmin[c * W + x]);
  for (int yy = lo2; yy < (cs << 3); ++yy) m = fminf(m, rowmin[yy * W + x]);
  for (int yy = (ce + 1) << 3; yy <= hi2; ++yy) m = fminf(m, rowmin[yy * W + x]);
  dc[p] = m;
  atomicAdd(&lh[__float_as_uint(m) >> 24], 1u);
  __syncthreads();
  unsigned c = lh[t];
  if (c) atomicAdd(&st->histA[0][t], c);
}

// ---------- radix histogram pass, levels 1..3 (dark channel select) ----------
__global__ __launch_bounds__(256) void k_hist(const float* __restrict__ data,
                                              unsigned (*hist)[256],
                                              int level, unsigned k0, int desc) {
  __shared__ unsigned lds[258];
  int t = threadIdx.x;
  unsigned prefix = 0u, k = k0;
  for (int j = 0; j < level; ++j) {
    unsigned ch, kn;
    resolve_level(hist[j], k, desc, lds, ch, kn);
    prefix |= ch << (24 - 8 * j);
    k = kn;
  }
  lds[t] = 0u;
  __syncthreads();
  int p = blockIdx.x * 256 + t;
  unsigned bits = __float_as_uint(data[p]);
  unsigned mask = 0xFFFFFFFFu << (32 - 8 * level);
  if ((bits & mask) == prefix)
    atomicAdd(&lds[(bits >> (24 - 8 * level)) & 0xFFu], 1u);
  __syncthreads();
  unsigned c = lds[t];
  if (c) atomicAdd(&hist[level][t], c);
}

// ---------- airlight gather ----------
__global__ __launch_bounds__(256) void k_gatherA(const float* __restrict__ dc,
                                                 const float* __restrict__ img, State* st) {
  __shared__ unsigned lds[258];
  unsigned vb, kf;
  resolve_prefix(st->histA, 230u, 1, 4, lds, vb, kf);
  int p = blockIdx.x * 256 + threadIdx.x;
  unsigned bits = __float_as_uint(dc[p]);
  if (bits > vb) {
    atomicAdd(&st->sumA[0], img[p]);
    atomicAdd(&st->sumA[1], img[HW + p]);
    atomicAdd(&st->sumA[2], img[2 * HW + p]);
  } else if (bits == vb) {
    unsigned pos = atomicAdd(&st->eqCount, 1u);
    if (pos < (unsigned)EQCAP) st->eqIdx[pos] = (unsigned)p;
  }
}

// lax.top_k tie-break = lower index first: keq smallest indices among equals
__global__ __launch_bounds__(256) void k_finalizeA(const float* __restrict__ img, State* st) {
  __shared__ unsigned lds[258];
  __shared__ unsigned sIdx[EQCAP];
  __shared__ float ssum[3];
  unsigned vb, keq;
  resolve_prefix(st->histA, 230u, 1, 4, lds, vb, keq);
  int t = threadIdx.x;
  unsigned ne = st->eqCount; if (ne > (unsigned)EQCAP) ne = EQCAP;
  for (int i = t; i < (int)ne; i += 256) sIdx[i] = st->eqIdx[i];
  if (t < 3) ssum[t] = 0.f;
  __syncthreads();
  unsigned lo = 0u, hi = HW;
  while (hi - lo > 1u) {
    unsigned mid = (lo + hi) >> 1;
    unsigned c = 0u;
    for (int i = t; i < (int)ne; i += 256) c += (sIdx[i] < mid) ? 1u : 0u;
    lds[t] = c; __syncthreads();
    for (int s = 128; s > 0; s >>= 1) { if (t < s) lds[t] += lds[t + s]; __syncthreads(); }
    unsigned total = lds[0];
    __syncthreads();
    if (total >= keq) hi = mid; else lo = mid;
  }
  float a0 = 0.f, a1 = 0.f, a2 = 0.f;
  for (int i = t; i < (int)ne; i += 256) {
    unsigned q = sIdx[i];
    if (q < hi) { a0 += img[q]; a1 += img[HW + q]; a2 += img[2 * HW + q]; }
  }
  atomicAdd(&ssum[0], a0); atomicAdd(&ssum[1], a1); atomicAdd(&ssum[2], a2);
  __syncthreads();
  if (t == 0) {
    st->A[0] = (st->sumA[0] + ssum[0]) / 230.0f;
    st->A[1] = (st->sumA[1] + ssum[1]) / 230.0f;
    st->A[2] = (st->sumA[2] + ssum[2]) / 230.0f;
  }
}

// ---------- S, V1, I, bccr pre-pool map ----------
__global__ __launch_bounds__(256) void k_elem1(const float* __restrict__ img,
                                               const State* __restrict__ st,
                                               float* __restrict__ So, float* __restrict__ Vo,
                                               float* __restrict__ Io, float* __restrict__ To) {
  int p = blockIdx.x * 256 + threadIdx.x;
  float A0 = st->A[0], A1 = st->A[1], A2 = st->A[2];
  float r = img[p], g = img[HW + p], bl = img[2 * HW + p];
  float nr = r / A0, ng = g / A1, nb = bl / A2;
  float mx = fmaxf(fmaxf(nr, ng), nb);
  float mn = fminf(fminf(nr, ng), nb);
  float d = mx + 1e-8f;
  So[p] = 1.0f - mn / d;
  Vo[p] = 1.0f / d;
  Io[p] = ((r + g) + bl) / 3.0f;
  const float c20 = (float)(20.0 / 255.0);
  const float c300 = (float)(300.0 / 255.0);
  float t0 = fmaxf((A0 - r) / (A0 - c20), (A0 - r) / (A0 - c300));
  float t1 = fmaxf((A1 - g) / (A1 - c20), (A1 - g) / (A1 - c300));
  float t2 = fmaxf((A2 - bl) / (A2 - c20), (A2 - bl) / (A2 - c300));
  To[p] = fmaxf(fmaxf(t0, t1), t2);
}

// ---------- wave reductions ----------
__device__ __forceinline__ float wred_sum(float v) { for (int m = 32; m; m >>= 1) v += __shfl_xor(v, m, 64); return v; }
__device__ __forceinline__ float wred_max(float v) { for (int m = 32; m; m >>= 1) v = fmaxf(v, __shfl_xor(v, m, 64)); return v; }
__device__ __forceinline__ float wred_min(float v) { for (int m = 32; m; m >>= 1) v = fminf(v, __shfl_xor(v, m, 64)); return v; }

// ---------- mega1: both patch grids (division-free slope test) + bccr H-maxpool ----------
__global__ __launch_bounds__(256) void k_mega1(const float* __restrict__ Sv,
                                               const float* __restrict__ Vv,
                                               const float* __restrict__ To,
                                               float* __restrict__ mh, State* st) {
  __shared__ float2 XY[PP];
  __shared__ float part[4][8];
  int b = blockIdx.x;
  int t = threadIdx.x;
  if (b >= 2048) {   // bccr 15-tap horizontal max (pad 0)
    int p = (b - 2048) * 256 + t;
    int y = p / W, x = p - y * W;
    float m = -INFINITY;
    for (int d = -7; d <= 7; ++d) {
      int xx = x + d;
      float v = ((unsigned)xx < (unsigned)W) ? To[y * W + xx] : 0.0f;
      m = fmaxf(m, v);
    }
    mh[p] = m;
    return;
  }
  int mode = b >> 10;              // 0: t1 grid, 1: shifted t2 grid
  int pid = b & 1023;
  int ph = pid >> 5, pw = pid & 31;
  if (t < PP) {
    int r = t / 15, c = t - (t / 15) * 15;
    int y, x;
    if (mode == 0) { y = ph * 15 + r; x = pw * 15 + c; }
    else {
      y = ph * 15 + r + 4; y = (y < 7) ? 7 : ((y > 479) ? 479 : y);
      x = pw * 15 + c + 4; x = (x < 7) ? 7 : ((x > 479) ? 479 : x);
    }
    float2 v; v.x = Vv[y * W + x]; v.y = Sv[y * W + x];
    XY[t] = v;
  }
  __syncthreads();
  float xi = 0.f, yi = 0.f;
  int cnt = 0;
  if (t < PP) {
    xi = XY[t].x; yi = XY[t].y;
    // slope = dY/(dX+1e-8) in (-1,0)  <=>  sign-resolved compares (no division)
    for (int j = 0; j < PP; ++j) {
      float2 o = XY[j];
      float dY = yi - o.y;
      float D = (xi - o.x) + 1e-8f;
      float nD = -D;
      bool c = (D > 0.0f) ? ((dY < 0.0f) && (dY > nD))
                          : ((D < 0.0f) && (dY > 0.0f) && (dY < nD));
      cnt += c ? 1 : 0;
    }
  }
  float pmf = (t < PP && cnt >= 113) ? 1.0f : 0.0f;   // scount >= 112.5
  float xm = xi * pmf, ym = yi * pmf;
  float v0 = wred_sum(pmf);
  float v1 = wred_sum(xm);
  float v2 = wred_sum(ym);
  float v3 = wred_sum(xm * ym);
  float v4 = wred_sum(xm * xm);
  float v5 = wred_max((t < PP) ? xm : -INFINITY);
  float v6 = wred_min((t < PP) ? (xi + 1e8f * (1.0f - pmf)) : INFINITY);
  int wid = t >> 6, lane = t & 63;
  if (lane == 0) {
    part[wid][0] = v0; part[wid][1] = v1; part[wid][2] = v2; part[wid][3] = v3;
    part[wid][4] = v4; part[wid][5] = v5; part[wid][6] = v6;
  }
  __syncthreads();
  if (t == 0) {
    float pcount = 0.f, sx = 0.f, sy = 0.f, sxy = 0.f, sxx = 0.f;
    float mxX = -INFINITY, mnX = INFINITY;
    for (int w2 = 0; w2 < 4; ++w2) {
      pcount += part[w2][0]; sx += part[w2][1]; sy += part[w2][2];
      sxy += part[w2][3]; sxx += part[w2][4];
      mxX = fmaxf(mxX, part[w2][5]); mnX = fminf(mnX, part[w2][6]);
    }
    float den = pcount + 1e-5f;
    float mxv = sx / den, myv = sy / den;
    float kk = (sxy - pcount * mxv * myv) / (sxx - pcount * (mxv * mxv) + 1e-5f);
    float bb = myv - kk * mxv;
    float tt = 1.0f + kk / (bb + 1e-8f);
    float len = sqrtf(1.0f + kk * kk) * (mxX - mnX);
    bool m = (pcount > 10.0f) && (len > 0.1f) && (kk > -1.0f) && (kk < 0.0f)
             && (tt > 0.01f) && (tt < 0.99f);
    float res = tt * (m ? 1.0f : 0.0f);   // keep JAX NaN*0 semantics
    if (mode == 0) st->tp1[pid] = res; else st->tp2[pid] = res;
  }
}

// ---------- bccr V-maxpool + clip ----------
__global__ __launch_bounds__(256) void k_maxV(const float* __restrict__ mh,
                                              float* __restrict__ tb) {
  int p = blockIdx.x * 256 + threadIdx.x;
  int y = p / W, x = p - y * W;
  float m = -INFINITY;
  for (int d = -7; d <= 7; ++d) {
    int yy = y + d;
    float v = ((unsigned)yy < (unsigned)HT) ? mh[yy * W + x] : 0.0f;
    m = fmaxf(m, v);
  }
  tb[p] = fminf(fmaxf(m, 0.05f), 1.0f);
}

// ---------- analytic percentile: t_slp is piecewise constant over <=4096 regions ----------
// Each tp1 patch (15x15) splits into <=2 row-groups x <=2 col-groups w.r.t. the
// shifted tp2 grid: ph==0 -> (7 rows b=0, 8 rows c2r=0); ph>=1 -> (4 rows c2r=ph-1,
// 11 rows c2r=ph); same for columns. Weighted 4-level radix select over (value, area).
__global__ __launch_bounds__(256) void k_pct(State* st) {
  __shared__ unsigned lh[256];
  __shared__ unsigned lds[258];
  __shared__ float tp1s[NPATCH], tp2s[NPATCH];
  int t = threadIdx.x;
  for (int i = t; i < NPATCH; i += 256) { tp1s[i] = st->tp1[i]; tp2s[i] = st->tp2[i]; }
  __syncthreads();
  unsigned prefix = 0u, k = 11521u;   // 1-based rank of sorted[11520]
  for (int level = 0; level < 4; ++level) {
    lh[t] = 0u;
    __syncthreads();
    unsigned mask = (level == 0) ? 0u : (0xFFFFFFFFu << (32 - 8 * level));
    int shift = 24 - 8 * level;
    for (int i = t; i < NPATCH; i += 256) {
      int ph = i >> 5, pw = i & 31;
      float a = tp1s[i];
      int rcnt[2], ridx[2], ccnt[2], cidx[2];
      if (ph == 0) { rcnt[0] = 7; ridx[0] = -1; rcnt[1] = 8; ridx[1] = 0; }
      else         { rcnt[0] = 4; ridx[0] = ph - 1; rcnt[1] = 11; ridx[1] = ph; }
      if (pw == 0) { ccnt[0] = 7; cidx[0] = -1; ccnt[1] = 8; cidx[1] = 0; }
      else         { ccnt[0] = 4; cidx[0] = pw - 1; ccnt[1] = 11; cidx[1] = pw; }
      for (int ri = 0; ri < 2; ++ri)
        for (int ci = 0; ci < 2; ++ci) {
          unsigned area = (unsigned)(rcnt[ri] * ccnt[ci]);
          float b = 0.0f;
          if (ridx[ri] >= 0 && cidx[ci] >= 0) b = tp2s[ridx[ri] * 32 + cidx[ci]];
          float r;
          if (a != 0.0f && b != 0.0f) r = (a + b) / 2.0f;
          else r = (a != 0.0f) ? a : b;
          float u = (r > 0.0f) ? r : 10.0f;            // where(t>0,t,10); NaN->10
          unsigned bits = __float_as_uint(u);
          if ((bits & mask) == prefix)
            atomicAdd(&lh[(bits >> shift) & 0xFFu], area);
        }
    }
    __syncthreads();
    unsigned ch, kn;
    resolve_level(lh, k, 0, lds, ch, kn);
    prefix |= ch << shift;
    k = kn;
  }
  if (t == 0) st->tminbits = prefix;
}

// ---------- guided filter pass 1 H, with fused t_fusion (P computed on the fly) ----------
__global__ __launch_bounds__(256) void k_gf1h_f(const float* __restrict__ I,
                                                const float* __restrict__ tb,
                                                const State* __restrict__ st,
                                                float* __restrict__ oI, float* __restrict__ oP,
                                                float* __restrict__ oIp, float* __restrict__ oII) {
  __shared__ float tp1s[NPATCH], tp2s[NPATCH];
  int t = threadIdx.x;
  for (int i = t; i < NPATCH; i += 256) { tp1s[i] = st->tp1[i]; tp2s[i] = st->tp2[i]; }
  __syncthreads();
  float tmin = __uint_as_float(st->tminbits);
  int p = blockIdx.x * 256 + t;
  int y = p / W, x = p - y * W;
  int c1row = (y / 15) * 32;
  bool c2ok = (y >= 7);
  int c2row = c2ok ? ((y - 4) / 15) * 32 : 0;
  float sI = 0.f, sP = 0.f, sIp = 0.f, sII = 0.f;
  for (int d = -30; d <= 30; ++d) {
    int xx = x + d;
    if ((unsigned)xx < (unsigned)W) {
      int q = y * W + xx;
      float a = tp1s[c1row + xx / 15];
      float b = 0.0f;
      if (c2ok && xx >= 7) b = tp2s[c2row + (xx - 4) / 15];
      float r;
      if (a != 0.0f && b != 0.0f) r = (a + b) / 2.0f;   // NaN != 0 true, as in JAX
      else r = (a != 0.0f) ? a : b;
      float v = (r > 0.0f) ? r : tb[q];                 // NaN -> tb
      v = (v < tmin) ? tmin : v;
      v = (v > 1.0f) ? 1.0f : v;
      float iv = I[q];
      sI += iv; sP += v; sIp += iv * v; sII += iv * iv;
    }
  }
  oI[p] = sI; oP[p] = sP; oIp[p] = sIp; oII[p] = sII;
}

// ---------- guided filter pass 1 V (direct, full-parallel) ----------
__global__ __launch_bounds__(256) void k_gf1v(const float* __restrict__ hI, const float* __restrict__ hP,
                                              const float* __restrict__ hIp, const float* __restrict__ hII,
                                              float* __restrict__ ao, float* __restrict__ bo) {
  int p = blockIdx.x * 256 + threadIdx.x;
  int y = p / W, x = p - y * W;
  float sI = 0.f, sP = 0.f, sIp = 0.f, sII = 0.f;
  for (int d = -30; d <= 30; ++d) {
    int yy = y + d;
    if ((unsigned)yy < (unsigned)HT) {
      int q = yy * W + x;
      sI += hI[q]; sP += hP[q]; sIp += hIp[q]; sII += hII[q];
    }
  }
  int ny = min(y + 30, HT - 1) - max(y - 30, 0) + 1;
  int nx = min(x + 30, W - 1) - max(x - 30, 0) + 1;
  float Nn = (float)(ny * nx);
  float mI = sI / Nn, mP = sP / Nn, mIp = sIp / Nn, mII = sII / Nn;
  float cov = mIp - mI * mP;
  float var = mII - mI * mI;
  float av = cov / (var + 1e-3f);
  ao[p] = av;
  bo[p] = mP - av * mI;
}

__global__ __launch_bounds__(256) void k_gf2h(const float* __restrict__ a, const float* __restrict__ b,
                                              float* __restrict__ oa, float* __restrict__ ob) {
  int p = blockIdx.x * 256 + threadIdx.x;
  int y = p / W, x = p - y * W;
  float sa = 0.f, sb = 0.f;
  for (int d = -30; d <= 30; ++d) {
    int xx = x + d;
    if ((unsigned)xx < (unsigned)W) { sa += a[y * W + xx]; sb += b[y * W + xx]; }
  }
  oa[p] = sa; ob[p] = sb;
}

__global__ __launch_bounds__(256) void k_gf2vfin(const float* __restrict__ ha, const float* __restrict__ hb,
                                                 const float* __restrict__ I, const float* __restrict__ img,
                                                 const State* __restrict__ st, float* __restrict__ out) {
  int p = blockIdx.x * 256 + threadIdx.x;
  int y = p / W, x = p - y * W;
  float sa = 0.f, sb = 0.f;
  for (int d = -30; d <= 30; ++d) {
    int yy = y + d;
    if ((unsigned)yy < (unsigned)HT) { int q = yy * W + x; sa += ha[q]; sb += hb[q]; }
  }
  int ny = min(y + 30, HT - 1) - max(y - 30, 0) + 1;
  int nx = min(x + 30, W - 1) - max(x - 30, 0) + 1;
  float Nn = (float)(ny * nx);
  float tref = (sa / Nn) * I[p] + (sb / Nn);
  float A0 = st->A[0], A1 = st->A[1], A2 = st->A[2];
  out[p]          = (img[p]          - A0) / tref + A0;
  out[HW + p]     = (img[HW + p]     - A1) / tref + A1;
  out[2 * HW + p] = (img[2 * HW + p] - A2) / tref + A2;
}

// ---------- launch: 17 dispatches ----------
extern "C" void kernel_launch(void* const* d_in, const int* in_sizes, int n_in,
                              void* d_out, int out_size, void* d_ws, size_t ws_size,
                              hipStream_t stream) {
  (void)in_sizes; (void)n_in; (void)out_size; (void)ws_size;
  const float* img = (const float*)d_in[0];
  float* out = (float*)d_out;
  State* st = (State*)d_ws;
  float* sb = (float*)((char*)d_ws + 65536);
  float* s0 = sb + 0 * HW;  // dmin -> dc -> tb
  float* s1 = sb + 1 * HW;  // minH temp -> To
  float* s2 = sb + 2 * HW;  // S -> a
  float* s3 = sb + 3 * HW;  // V1 -> b
  float* s4 = sb + 4 * HW;  // I (channel mean)
  float* s5 = sb + 5 * HW;  // cmin -> mh
  float* s6 = sb + 6 * HW;  // box temps
  float* s7 = sb + 7 * HW;
  float* s8 = sb + 8 * HW;
  float* s9 = sb + 9 * HW;

  dim3 blk(256);
  dim3 ge(GE);

  k0_init_dmin<<<ge, blk, 0, stream>>>(img, s0, st);
  k_minH<<<ge, blk, 0, stream>>>(s0, s1);
  k_vchunk<<<dim3(113), blk, 0, stream>>>(s1, s5);
  k_minV2<<<ge, blk, 0, stream>>>(s1, s5, s0, st);          // dc + histA[0]

  for (int l = 1; l < 4; ++l)
    k_hist<<<ge, blk, 0, stream>>>(s0, st->histA, l, 230u, 1);
  k_gatherA<<<ge, blk, 0, stream>>>(s0, img, st);
  k_finalizeA<<<dim3(1), blk, 0, stream>>>(img, st);

  k_elem1<<<ge, blk, 0, stream>>>(img, st, s2, s3, s4, s1);

  k_mega1<<<dim3(2048 + GE), blk, 0, stream>>>(s2, s3, s1, s5, st);
  k_maxV<<<ge, blk, 0, stream>>>(s5, s0);                   // tb
  k_pct<<<dim3(1), blk, 0, stream>>>(st);                   // tmin (analytic)

  k_gf1h_f<<<ge, blk, 0, stream>>>(s4, s0, st, s6, s7, s8, s9);
  k_gf1v<<<ge, blk, 0, stream>>>(s6, s7, s8, s9, s2, s3);
  k_gf2h<<<ge, blk, 0, stream>>>(s2, s3, s6, s7);
  k_gf2vfin<<<ge, blk, 0, stream>>>(s6, s7, s4, img, st, out);
}

// Round 5
// 192.718 us; speedup vs baseline: 1.8649x; 1.3813x over previous
//
#include <hip/hip_runtime.h>
#include <math.h>

#define W 480
#define HT 480
#define HW (W*HT)
#define GE (HW/256)     // 900 blocks of 256
#define PP 225
#define NPATCH 1024
#define EQCAP 8192

struct State {
  unsigned histA[4][256];   // dark-channel top-k select (descending, k=230)
  unsigned slotP[4];        // cached resolved prefix after level l
  unsigned slotK[4];        // cached remaining rank after level l
  float sumA[3];
  unsigned eqCount;
  float A[3];
  unsigned tminbits;        // percentile result (float bits)
  unsigned eqIdx[EQCAP];
  float tp1[NPATCH];
  float tp2[NPATCH];
};

// ---------- cooperative radix-select resolve (256 threads) ----------
__device__ __forceinline__ void resolve_level(const unsigned* __restrict__ h,
                                              unsigned k_in, int desc,
                                              unsigned* lds,
                                              unsigned& chosen, unsigned& k_out) {
  int t = threadIdx.x;
  unsigned c = h[desc ? (255 - t) : t];
  lds[t] = c;
  __syncthreads();
  for (int s = 1; s < 256; s <<= 1) {           // Hillis-Steele inclusive scan
    unsigned add = (t >= s) ? lds[t - s] : 0u;
    __syncthreads();
    lds[t] += add;
    __syncthreads();
  }
  unsigned incl = lds[t];
  unsigned excl = incl - c;
  if (incl >= k_in && excl < k_in) { lds[256] = (unsigned)t; lds[257] = k_in - excl; }
  __syncthreads();
  unsigned tt = lds[256];
  k_out = lds[257];
  chosen = desc ? (255u - tt) : tt;
  __syncthreads();
}

// ---------- 1: init + channel-min + horizontal 55-min (one row per block) ----------
__global__ __launch_bounds__(512) void k_rowmin(const float* __restrict__ img,
                                                float* __restrict__ rowmin, State* st) {
  __shared__ float l[534];
  int y = blockIdx.x, t = threadIdx.x;
  for (int i = t; i < 534; i += 512) {
    int col = i - 27;
    float v = 1.0f;                              // pad value (constant_values=1.0)
    if ((unsigned)col < (unsigned)W) {
      int q = y * W + col;
      v = fminf(fminf(img[q], img[HW + q]), img[2 * HW + q]);
    }
    l[i] = v;
  }
  if (y == 0 && t < 256) {
    for (int i = 0; i < 4; ++i) st->histA[i][t] = 0u;
    if (t == 0) { st->sumA[0] = 0.f; st->sumA[1] = 0.f; st->sumA[2] = 0.f; st->eqCount = 0u; }
  }
  __syncthreads();
  if (t < W) {
    float m = l[t];
    for (int d = 1; d < 55; ++d) m = fminf(m, l[t + d]);
    rowmin[y * W + t] = m;
  }
}

// ---------- 2: vertical 8-row chunk mins (60 chunks x 480 cols) ----------
__global__ __launch_bounds__(256) void k_vchunk(const float* __restrict__ rowmin,
                                                float* __restrict__ cmin) {
  int p = blockIdx.x * 256 + threadIdx.x;
  if (p >= 60 * W) return;
  int c = p / W, x = p - c * W;
  float m = INFINITY;
  for (int r = 0; r < 8; ++r) m = fminf(m, rowmin[(c * 8 + r) * W + x]);
  cmin[p] = m;
}

// ---------- 3: vertical 55-min via chunks + edges, fused histA level-0 ----------
__global__ __launch_bounds__(256) void k_minV2(const float* __restrict__ rowmin,
                                               const float* __restrict__ cmin,
                                               float* __restrict__ dc, State* st) {
  __shared__ unsigned lh[256];
  int t = threadIdx.x;
  lh[t] = 0u;
  __syncthreads();
  int p = blockIdx.x * 256 + t;
  int y = p / W, x = p - y * W;
  int lo = y - 27, hi = y + 27;
  float m = (lo < 0 || hi >= HT) ? 1.0f : INFINITY;
  int lo2 = max(lo, 0), hi2 = min(hi, HT - 1);
  int cs = (lo2 + 7) >> 3, ce = ((hi2 + 1) >> 3) - 1;
  for (int c = cs; c <= ce; ++c) m = fminf(m, cmin[c * W + x]);
  for (int yy = lo2; yy < (cs << 3); ++yy) m = fminf(m, rowmin[yy * W + x]);
  for (int yy = (ce + 1) << 3; yy <= hi2; ++yy) m = fminf(m, rowmin[yy * W + x]);
  dc[p] = m;
  atomicAdd(&lh[__float_as_uint(m) >> 24], 1u);
  __syncthreads();
  unsigned c = lh[t];
  if (c) atomicAdd(&st->histA[0][t], c);
}

// ---------- 4-6: radix histogram pass, resolves exactly ONE level, caches it ----------
__global__ __launch_bounds__(256) void k_hist(const float* __restrict__ dc,
                                              State* st, int level) {
  __shared__ unsigned lds[258];
  int t = threadIdx.x;
  unsigned prefix, k;
  if (level == 1) { prefix = 0u; k = 230u; }
  else { prefix = st->slotP[level - 2]; k = st->slotK[level - 2]; }
  unsigned ch, kn;
  resolve_level(st->histA[level - 1], k, 1, lds, ch, kn);
  prefix |= ch << (32 - 8 * level);
  k = kn;
  if (t == 0) { st->slotP[level - 1] = prefix; st->slotK[level - 1] = k; }
  __syncthreads();
  lds[t] = 0u;
  __syncthreads();
  int p = blockIdx.x * 256 + t;
  unsigned bits = __float_as_uint(dc[p]);
  unsigned mask = 0xFFFFFFFFu << (32 - 8 * level);
  if ((bits & mask) == prefix)
    atomicAdd(&lds[(bits >> (24 - 8 * level)) & 0xFFu], 1u);
  __syncthreads();
  unsigned c = lds[t];
  if (c) atomicAdd(&st->histA[level][t], c);
}

// ---------- 7: airlight gather (resolves last level, caches final threshold) ----------
__global__ __launch_bounds__(256) void k_gatherA(const float* __restrict__ dc,
                                                 const float* __restrict__ img, State* st) {
  __shared__ unsigned lds[258];
  int t = threadIdx.x;
  unsigned prefix = st->slotP[2], k = st->slotK[2];
  unsigned ch, kn;
  resolve_level(st->histA[3], k, 1, lds, ch, kn);
  unsigned vb = prefix | ch;
  if (t == 0) { st->slotP[3] = vb; st->slotK[3] = kn; }
  int p = blockIdx.x * 256 + t;
  unsigned bits = __float_as_uint(dc[p]);
  if (bits > vb) {
    atomicAdd(&st->sumA[0], img[p]);
    atomicAdd(&st->sumA[1], img[HW + p]);
    atomicAdd(&st->sumA[2], img[2 * HW + p]);
  } else if (bits == vb) {
    unsigned pos = atomicAdd(&st->eqCount, 1u);
    if (pos < (unsigned)EQCAP) st->eqIdx[pos] = (unsigned)p;
  }
}

// ---------- 8: tie-break (lower index first) via 3-level radix select on indices ----------
__global__ __launch_bounds__(256) void k_finalizeA(const float* __restrict__ img, State* st) {
  __shared__ unsigned lds[258];
  __shared__ unsigned lh[256];
  __shared__ unsigned sIdx[EQCAP];
  __shared__ float ssum[3];
  int t = threadIdx.x;
  unsigned keq = st->slotK[3];
  unsigned ne = st->eqCount; if (ne > (unsigned)EQCAP) ne = EQCAP;
  for (int i = t; i < (int)ne; i += 256) sIdx[i] = st->eqIdx[i];
  if (t < 3) ssum[t] = 0.f;
  __syncthreads();
  // indices < 2^18; 3 bytes: shifts 16, 8, 0; ascending select of keq-th smallest
  unsigned pfx = 0u, k = keq;
  for (int lev = 0; lev < 3; ++lev) {
    int s = 16 - 8 * lev;
    lh[t] = 0u;
    __syncthreads();
    for (int i = t; i < (int)ne; i += 256) {
      unsigned v = sIdx[i];
      if ((v >> (s + 8)) == (pfx >> (s + 8)))
        atomicAdd(&lh[(v >> s) & 0xFFu], 1u);
    }
    __syncthreads();
    unsigned ch, kn;
    resolve_level(lh, k, 0, lds, ch, kn);
    pfx |= ch << s;
    k = kn;
  }
  // pfx = keq-th smallest candidate index; take all idx <= pfx
  float a0 = 0.f, a1 = 0.f, a2 = 0.f;
  for (int i = t; i < (int)ne; i += 256) {
    unsigned q = sIdx[i];
    if (q <= pfx) { a0 += img[q]; a1 += img[HW + q]; a2 += img[2 * HW + q]; }
  }
  atomicAdd(&ssum[0], a0); atomicAdd(&ssum[1], a1); atomicAdd(&ssum[2], a2);
  __syncthreads();
  if (t == 0) {
    st->A[0] = (st->sumA[0] + ssum[0]) / 230.0f;
    st->A[1] = (st->sumA[1] + ssum[1]) / 230.0f;
    st->A[2] = (st->sumA[2] + ssum[2]) / 230.0f;
  }
}

// ---------- 9: SV (packed), I, bccr pre-pool map ----------
__global__ __launch_bounds__(256) void k_elem1(const float* __restrict__ img,
                                               const State* __restrict__ st,
                                               float2* __restrict__ SV,
                                               float* __restrict__ Io, float* __restrict__ To) {
  int p = blockIdx.x * 256 + threadIdx.x;
  float A0 = st->A[0], A1 = st->A[1], A2 = st->A[2];
  float r = img[p], g = img[HW + p], bl = img[2 * HW + p];
  float nr = r / A0, ng = g / A1, nb = bl / A2;
  float mx = fmaxf(fmaxf(nr, ng), nb);
  float mn = fminf(fminf(nr, ng), nb);
  float d = mx + 1e-8f;
  float S = 1.0f - mn / d;
  float V = 1.0f / d;
  SV[p] = make_float2(V, S);   // x = X (V1), y = Y (S)
  Io[p] = ((r + g) + bl) / 3.0f;
  const float c20 = (float)(20.0 / 255.0);
  const float c300 = (float)(300.0 / 255.0);
  float t0 = fmaxf((A0 - r) / (A0 - c20), (A0 - r) / (A0 - c300));
  float t1 = fmaxf((A1 - g) / (A1 - c20), (A1 - g) / (A1 - c300));
  float t2 = fmaxf((A2 - bl) / (A2 - c20), (A2 - bl) / (A2 - c300));
  To[p] = fmaxf(fmaxf(t0, t1), t2);
}

// ---------- wave reductions ----------
__device__ __forceinline__ float wred_sum(float v) { for (int m = 32; m; m >>= 1) v += __shfl_xor(v, m, 64); return v; }
__device__ __forceinline__ float wred_max(float v) { for (int m = 32; m; m >>= 1) v = fmaxf(v, __shfl_xor(v, m, 64)); return v; }
__device__ __forceinline__ float wred_min(float v) { for (int m = 32; m; m >>= 1) v = fminf(v, __shfl_xor(v, m, 64)); return v; }

// ---------- 10: both patch grids (sign/magnitude slope test) + bccr H-maxpool ----------
__global__ __launch_bounds__(256) void k_mega1(const float2* __restrict__ SV,
                                               const float* __restrict__ To,
                                               float* __restrict__ mh, State* st) {
  __shared__ float2 XY[PP];
  __shared__ float part[4][8];
  int b = blockIdx.x;
  int t = threadIdx.x;
  if (b >= 2048) {   // bccr 15-tap horizontal max (pad 0)
    int p = (b - 2048) * 256 + t;
    int y = p / W, x = p - y * W;
    float m = -INFINITY;
    for (int d = -7; d <= 7; ++d) {
      int xx = x + d;
      float v = ((unsigned)xx < (unsigned)W) ? To[y * W + xx] : 0.0f;
      m = fmaxf(m, v);
    }
    mh[p] = m;
    return;
  }
  int mode = b >> 10;              // 0: t1 grid, 1: shifted t2 grid
  int pid = b & 1023;
  int ph = pid >> 5, pw = pid & 31;
  if (t < PP) {
    int r = t / 15, c = t - (t / 15) * 15;
    int y, x;
    if (mode == 0) { y = ph * 15 + r; x = pw * 15 + c; }
    else {
      y = ph * 15 + r + 4; y = (y < 7) ? 7 : ((y > 479) ? 479 : y);
      x = pw * 15 + c + 4; x = (x < 7) ? 7 : ((x > 479) ? 479 : x);
    }
    XY[t] = SV[y * W + x];
  }
  __syncthreads();
  float xi = 0.f, yi = 0.f;
  int cnt = 0;
  if (t < PP) {
    xi = XY[t].x; yi = XY[t].y;
    // slope = dY/(dX+1e-8) in (-1,0)  <=>  dY*D < 0  AND  |dY| < |D|
    for (int j = 0; j < PP; ++j) {
      float2 o = XY[j];
      float dY = yi - o.y;
      float D = (xi - o.x) + 1e-8f;
      cnt += ((dY * D < 0.0f) && (fabsf(dY) < fabsf(D))) ? 1 : 0;
    }
  }
  float pmf = (t < PP && cnt >= 113) ? 1.0f : 0.0f;   // scount >= 112.5
  float xm = xi * pmf, ym = yi * pmf;
  float v0 = wred_sum(pmf);
  float v1 = wred_sum(xm);
  float v2 = wred_sum(ym);
  float v3 = wred_sum(xm * ym);
  float v4 = wred_sum(xm * xm);
  float v5 = wred_max((t < PP) ? xm : -INFINITY);
  float v6 = wred_min((t < PP) ? (xi + 1e8f * (1.0f - pmf)) : INFINITY);
  int wid = t >> 6, lane = t & 63;
  if (lane == 0) {
    part[wid][0] = v0; part[wid][1] = v1; part[wid][2] = v2; part[wid][3] = v3;
    part[wid][4] = v4; part[wid][5] = v5; part[wid][6] = v6;
  }
  __syncthreads();
  if (t == 0) {
    float pcount = 0.f, sx = 0.f, sy = 0.f, sxy = 0.f, sxx = 0.f;
    float mxX = -INFINITY, mnX = INFINITY;
    for (int w2 = 0; w2 < 4; ++w2) {
      pcount += part[w2][0]; sx += part[w2][1]; sy += part[w2][2];
      sxy += part[w2][3]; sxx += part[w2][4];
      mxX = fmaxf(mxX, part[w2][5]); mnX = fminf(mnX, part[w2][6]);
    }
    float den = pcount + 1e-5f;
    float mxv = sx / den, myv = sy / den;
    float kk = (sxy - pcount * mxv * myv) / (sxx - pcount * (mxv * mxv) + 1e-5f);
    float bb = myv - kk * mxv;
    float tt = 1.0f + kk / (bb + 1e-8f);
    float len = sqrtf(1.0f + kk * kk) * (mxX - mnX);
    bool m = (pcount > 10.0f) && (len > 0.1f) && (kk > -1.0f) && (kk < 0.0f)
             && (tt > 0.01f) && (tt < 0.99f);
    float res = tt * (m ? 1.0f : 0.0f);   // keep JAX NaN*0 semantics
    if (mode == 0) st->tp1[pid] = res; else st->tp2[pid] = res;
  }
}

// ---------- 11: bccr V-maxpool+clip (blocks 0..GE-1) | analytic percentile (block GE) ----------
__global__ __launch_bounds__(256) void k_maxV_pct(const float* __restrict__ mh,
                                                  float* __restrict__ tb, State* st) {
  __shared__ unsigned lh[256];
  __shared__ unsigned lds[258];
  __shared__ float tp1s[NPATCH], tp2s[NPATCH];
  int b = blockIdx.x;
  int t = threadIdx.x;
  if (b < GE) {
    int p = b * 256 + t;
    int y = p / W, x = p - y * W;
    float m = -INFINITY;
    for (int d = -7; d <= 7; ++d) {
      int yy = y + d;
      float v = ((unsigned)yy < (unsigned)HT) ? mh[yy * W + x] : 0.0f;
      m = fmaxf(m, v);
    }
    tb[p] = fminf(fmaxf(m, 0.05f), 1.0f);
    return;
  }
  // percentile: t_slp piecewise constant over <=4096 (value, area) regions
  for (int i = t; i < NPATCH; i += 256) { tp1s[i] = st->tp1[i]; tp2s[i] = st->tp2[i]; }
  __syncthreads();
  unsigned prefix = 0u, k = 11521u;   // 1-based rank of sorted[11520]
  for (int level = 0; level < 4; ++level) {
    lh[t] = 0u;
    __syncthreads();
    unsigned mask = (level == 0) ? 0u : (0xFFFFFFFFu << (32 - 8 * level));
    int shift = 24 - 8 * level;
    for (int i = t; i < NPATCH; i += 256) {
      int ph = i >> 5, pw = i & 31;
      float a = tp1s[i];
      int rcnt[2], ridx[2], ccnt[2], cidx[2];
      if (ph == 0) { rcnt[0] = 7; ridx[0] = -1; rcnt[1] = 8; ridx[1] = 0; }
      else         { rcnt[0] = 4; ridx[0] = ph - 1; rcnt[1] = 11; ridx[1] = ph; }
      if (pw == 0) { ccnt[0] = 7; cidx[0] = -1; ccnt[1] = 8; cidx[1] = 0; }
      else         { ccnt[0] = 4; cidx[0] = pw - 1; ccnt[1] = 11; cidx[1] = pw; }
      for (int ri = 0; ri < 2; ++ri)
        for (int ci = 0; ci < 2; ++ci) {
          unsigned area = (unsigned)(rcnt[ri] * ccnt[ci]);
          float bb = 0.0f;
          if (ridx[ri] >= 0 && cidx[ci] >= 0) bb = tp2s[ridx[ri] * 32 + cidx[ci]];
          float r;
          if (a != 0.0f && bb != 0.0f) r = (a + bb) / 2.0f;
          else r = (a != 0.0f) ? a : bb;
          float u = (r > 0.0f) ? r : 10.0f;            // where(t>0,t,10); NaN->10
          unsigned bits = __float_as_uint(u);
          if ((bits & mask) == prefix)
            atomicAdd(&lh[(bits >> shift) & 0xFFu], area);
        }
    }
    __syncthreads();
    unsigned ch, kn;
    resolve_level(lh, k, 0, lds, ch, kn);
    prefix |= ch << shift;
    k = kn;
  }
  if (t == 0) st->tminbits = prefix;
}

// ---------- 12: gf pass-1 horizontal (one row/block), fused t_fusion, float4 out ----------
__global__ __launch_bounds__(512) void k_gf1h(const float* __restrict__ I,
                                              const float* __restrict__ tb,
                                              const State* __restrict__ st,
                                              float4* __restrict__ box4) {
  __shared__ float tp1s[NPATCH], tp2s[NPATCH];
  __shared__ float Pl[540], Il[540];
  int y = blockIdx.x, t = threadIdx.x;
  for (int i = t; i < NPATCH; i += 512) { tp1s[i] = st->tp1[i]; tp2s[i] = st->tp2[i]; }
  __syncthreads();
  float tmin = __uint_as_float(st->tminbits);
  int c1row = (y / 15) * 32;
  bool c2ok = (y >= 7);
  int c2row = c2ok ? ((y - 4) / 15) * 32 : 0;
  for (int i = t; i < 540; i += 512) {
    int col = i - 30;
    float pv = 0.0f, iv = 0.0f;
    if ((unsigned)col < (unsigned)W) {
      int q = y * W + col;
      float a = tp1s[c1row + col / 15];
      float bb = 0.0f;
      if (c2ok && col >= 7) bb = tp2s[c2row + (col - 4) / 15];
      float r;
      if (a != 0.0f && bb != 0.0f) r = (a + bb) / 2.0f;   // NaN != 0 true, as in JAX
      else r = (a != 0.0f) ? a : bb;
      float v = (r > 0.0f) ? r : tb[q];                   // NaN -> tb
      v = (v < tmin) ? tmin : v;
      v = (v > 1.0f) ? 1.0f : v;
      pv = v; iv = I[q];
    }
    Pl[i] = pv; Il[i] = iv;
  }
  __syncthreads();
  if (t < W) {
    float sI = 0.f, sP = 0.f, sIp = 0.f, sII = 0.f;
    for (int d = 0; d < 61; ++d) {
      float iv = Il[t + d], pv = Pl[t + d];
      sI += iv; sP += pv; sIp += iv * pv; sII += iv * iv;
    }
    box4[y * W + t] = make_float4(sI, sP, sIp, sII);
  }
}

// ---------- 13: gf pass-1 vertical, float4 in, float2 (a,b) out ----------
__global__ __launch_bounds__(256) void k_gf1v(const float4* __restrict__ box4,
                                              float2* __restrict__ ab) {
  int p = blockIdx.x * 256 + threadIdx.x;
  int y = p / W, x = p - y * W;
  float sI = 0.f, sP = 0.f, sIp = 0.f, sII = 0.f;
  for (int d = -30; d <= 30; ++d) {
    int yy = y + d;
    if ((unsigned)yy < (unsigned)HT) {
      float4 v = box4[yy * W + x];
      sI += v.x; sP += v.y; sIp += v.z; sII += v.w;
    }
  }
  int ny = min(y + 30, HT - 1) - max(y - 30, 0) + 1;
  int nx = min(x + 30, W - 1) - max(x - 30, 0) + 1;
  float Nn = (float)(ny * nx);
  float mI = sI / Nn, mP = sP / Nn, mIp = sIp / Nn, mII = sII / Nn;
  float cov = mIp - mI * mP;
  float var = mII - mI * mI;
  float av = cov / (var + 1e-3f);
  ab[p] = make_float2(av, mP - av * mI);
}

// ---------- 14: gf pass-2 horizontal (one row/block), float2 in/out ----------
__global__ __launch_bounds__(512) void k_gf2h(const float2* __restrict__ ab,
                                              float2* __restrict__ hab) {
  __shared__ float2 l[540];
  int y = blockIdx.x, t = threadIdx.x;
  for (int i = t; i < 540; i += 512) {
    int col = i - 30;
    float2 v = make_float2(0.f, 0.f);
    if ((unsigned)col < (unsigned)W) v = ab[y * W + col];
    l[i] = v;
  }
  __syncthreads();
  if (t < W) {
    float sa = 0.f, sb = 0.f;
    for (int d = 0; d < 61; ++d) { float2 v = l[t + d]; sa += v.x; sb += v.y; }
    hab[y * W + t] = make_float2(sa, sb);
  }
}

// ---------- 15: gf pass-2 vertical + restore epilogue ----------
__global__ __launch_bounds__(256) void k_gf2vfin(const float2* __restrict__ hab,
                                                 const float* __restrict__ I,
                                                 const float* __restrict__ img,
                                                 const State* __restrict__ st,
                                                 float* __restrict__ out) {
  int p = blockIdx.x * 256 + threadIdx.x;
  int y = p / W, x = p - y * W;
  float sa = 0.f, sb = 0.f;
  for (int d = -30; d <= 30; ++d) {
    int yy = y + d;
    if ((unsigned)yy < (unsigned)HT) { float2 v = hab[yy * W + x]; sa += v.x; sb += v.y; }
  }
  int ny = min(y + 30, HT - 1) - max(y - 30, 0) + 1;
  int nx = min(x + 30, W - 1) - max(x - 30, 0) + 1;
  float Nn = (float)(ny * nx);
  float tref = (sa / Nn) * I[p] + (sb / Nn);
  float A0 = st->A[0], A1 = st->A[1], A2 = st->A[2];
  out[p]          = (img[p]          - A0) / tref + A0;
  out[HW + p]     = (img[HW + p]     - A1) / tref + A1;
  out[2 * HW + p] = (img[2 * HW + p] - A2) / tref + A2;
}

// ---------- launch: 15 dispatches ----------
extern "C" void kernel_launch(void* const* d_in, const int* in_sizes, int n_in,
                              void* d_out, int out_size, void* d_ws, size_t ws_size,
                              hipStream_t stream) {
  (void)in_sizes; (void)n_in; (void)out_size; (void)ws_size;
  const float* img = (const float*)d_in[0];
  float* out = (float*)d_out;
  State* st = (State*)d_ws;
  float* sb = (float*)((char*)d_ws + 65536);
  // layout (floats): A=dc/tb [0,HW) ; B=rowmin/To [HW,2HW) ; D=I [2HW,3HW) ;
  // F=[3HW,7HW): SV(2HW)+cmin+mh early, box4 later, hab later ; G=ab [7HW,9HW)
  float* bufA = sb;                 // dc -> tb
  float* bufB = sb + HW;            // rowmin -> To
  float* bufD = sb + 2 * HW;        // I
  float* bufF = sb + 3 * HW;        // SV | cmin | mh -> box4 -> hab
  float2* SV   = (float2*)bufF;               // [3HW,5HW)
  float* cmin  = bufF + 2 * HW;               // [5HW,5HW+28800)
  float* mh    = bufF + 3 * HW;               // [6HW,7HW)
  float4* box4 = (float4*)bufF;               // [3HW,7HW)
  float2* hab  = (float2*)bufF;               // [3HW,5HW)
  float2* ab   = (float2*)(sb + 7 * HW);      // [7HW,9HW)

  dim3 b256(256), b512(512);
  dim3 ge(GE), rows(HT);

  k_rowmin<<<rows, b512, 0, stream>>>(img, bufB, st);
  k_vchunk<<<dim3(113), b256, 0, stream>>>(bufB, cmin);
  k_minV2<<<ge, b256, 0, stream>>>(bufB, cmin, bufA, st);       // dc + histA[0]
  for (int l = 1; l < 4; ++l)
    k_hist<<<ge, b256, 0, stream>>>(bufA, st, l);
  k_gatherA<<<ge, b256, 0, stream>>>(bufA, img, st);
  k_finalizeA<<<dim3(1), b256, 0, stream>>>(img, st);
  k_elem1<<<ge, b256, 0, stream>>>(img, st, SV, bufD, bufB);    // SV, I, To
  k_mega1<<<dim3(2048 + GE), b256, 0, stream>>>(SV, bufB, mh, st);
  k_maxV_pct<<<dim3(GE + 1), b256, 0, stream>>>(mh, bufA, st);  // tb + tmin
  k_gf1h<<<rows, b512, 0, stream>>>(bufD, bufA, st, box4);
  k_gf1v<<<ge, b256, 0, stream>>>(box4, ab);
  k_gf2h<<<rows, b512, 0, stream>>>(ab, hab);
  k_gf2vfin<<<ge, b256, 0, stream>>>(hab, bufD, img, st, out);
}